// Round 8
// baseline (354.016 us; speedup 1.0000x reference)
//
#include <hip/hip_runtime.h>

typedef unsigned short u16;
typedef unsigned int u32;
typedef _Float16 F16;
typedef __attribute__((ext_vector_type(8))) _Float16 h8v;     // fp16 MFMA fragment (4 VGPR)
typedef __attribute__((ext_vector_type(4))) _Float16 h4v;
typedef __attribute__((ext_vector_type(4))) float f32x4;      // MFMA accumulator

#define DEV __device__ __forceinline__

DEV void gld16(const void* g, void* l) {
  __builtin_amdgcn_global_load_lds((const __attribute__((address_space(1))) void*)g,
                                   (__attribute__((address_space(3))) void*)l, 16, 0, 0);
}
DEV f32x4 mfma16(h8v a, h8v b, f32x4 c) {
  return __builtin_amdgcn_mfma_f32_16x16x32_f16(a, b, c, 0, 0, 0);
}

// LPT schedule: 24 ords x 32 bn = 768 jobs, 3 per CU (ords o, o+8, o+16 share a CU),
// every CU's 3 jobs sum to exactly 34 kv-tiles. seg: 0=first half, 1=second half, 2=full.
__device__ __constant__ int QT_TAB[24]  = {15,7,14,14,13,6,12,11, 15,13,12,10,10,9,11,5, 0,1,2,3,8,9,8,4};
__device__ __constant__ int SEG_TAB[24] = { 0,2, 0, 1, 1,2, 1, 1,  1, 0, 0, 0, 1,0, 0,2, 2,2,2,2,1,1,0,2};

// ---------------- convert fp32 -> fp16: x then wq|wk|wv in one launch ----------------
__global__ void __launch_bounds__(256) k_split_all(const float* __restrict__ x,
                                                   const float* __restrict__ wq,
                                                   const float* __restrict__ wk,
                                                   const float* __restrict__ wv,
                                                   F16* __restrict__ xh, F16* __restrict__ wh) {
  int i = blockIdx.x * 256 + threadIdx.x;            // group of 8 elems
  const float* src; F16* dst; int li;
  if (i < 1048576)      { src = x;  dst = xh;            li = i; }
  else if (i < 1179648) { src = wq; dst = wh;            li = i - 1048576; }
  else if (i < 1310720) { src = wk; dst = wh + 1048576;  li = i - 1179648; }
  else                  { src = wv; dst = wh + 2097152;  li = i - 1310720; }
  const float4* p = (const float4*)src + (size_t)li * 2;
  float4 a = p[0], b = p[1];
  float v[8] = {a.x, a.y, a.z, a.w, b.x, b.y, b.z, b.w};
  h8v o;
#pragma unroll
  for (int j = 0; j < 8; ++j) o[j] = (F16)v[j];
  ((h8v*)dst)[li] = o;
}

// ---------------- fused QKV fp16 GEMM (unchanged) ----------------
__global__ void __launch_bounds__(256, 3) k_gemm_qkv(
    const F16* __restrict__ A, const F16* __restrict__ W,
    F16* __restrict__ qf, F16* __restrict__ kf, F16* __restrict__ vf) {
  __shared__ F16 lds[16384];                 // 32KB: A-tile, B-tile [128][64], 8 16B-units/row, unit^=(row&7)
  F16* sA = lds;
  F16* sB = lds + 8192;
  const int tid = threadIdx.x;
  const int lane = tid & 63, w = tid >> 6;
  const int wm = w >> 1, wn = w & 1;
  const int l15 = lane & 15, g = lane >> 4;
  const int bid = blockIdx.x;
  const int mt = bid & 63, nt = bid >> 6;    // nt 0..23
  const F16* B = W + (size_t)(nt >> 3) * 1048576;
  F16* C = (nt < 8) ? qf : (nt < 16) ? kf : vf;
  const int m0 = mt * 128;
  const int n0 = (nt & 7) * 128;

  f32x4 acc[4][4] = {};

  for (int kt = 0; kt < 16; ++kt) {
    const int k0 = kt * 64;
#pragma unroll
    for (int p = 0; p < 4; ++p) {
      int u = p * 256 + tid;
      int row = u >> 3, jp = u & 7;
      int j = jp ^ (row & 7);               // pre-swizzled global source, linear LDS dest
      size_t ga = (size_t)(m0 + row) * 1024 + k0 + j * 8;
      size_t gb = (size_t)(n0 + row) * 1024 + k0 + j * 8;
      gld16(A + ga, sA + u * 8);
      gld16(B + gb, sB + u * 8);
    }
    __syncthreads();
#pragma unroll
    for (int ks = 0; ks < 2; ++ks) {
      h8v fa[4], fb[4];
#pragma unroll
      for (int mf = 0; mf < 4; ++mf) {
        int row = wm * 64 + mf * 16 + l15;
        int off = row * 64 + (((ks * 4 + g) ^ (row & 7)) * 8);
        fa[mf] = *(const h8v*)(sA + off);
      }
#pragma unroll
      for (int nf = 0; nf < 4; ++nf) {
        int row = wn * 64 + nf * 16 + l15;
        int off = row * 64 + (((ks * 4 + g) ^ (row & 7)) * 8);
        fb[nf] = *(const h8v*)(sB + off);
      }
#pragma unroll
      for (int mf = 0; mf < 4; ++mf)
#pragma unroll
        for (int nf = 0; nf < 4; ++nf)
          acc[mf][nf] = mfma16(fa[mf], fb[nf], acc[mf][nf]);
    }
    __syncthreads();
  }
#pragma unroll
  for (int mf = 0; mf < 4; ++mf)
#pragma unroll
    for (int nf = 0; nf < 4; ++nf)
#pragma unroll
      for (int r = 0; r < 4; ++r) {
        int m = m0 + wm * 64 + mf * 16 + g * 4 + r;   // C/D: col=lane&15, row=(lane>>4)*4+r
        int n = n0 + wn * 64 + nf * 16 + l15;
        C[(size_t)m * 1024 + n] = (F16)acc[mf][nf][r];
      }
}

// ---------------- fused prep: rope(q&k) + V transpose (unchanged) ----------------
__global__ void __launch_bounds__(256) k_prep(const F16* __restrict__ qf, const F16* __restrict__ kf,
                                              const F16* __restrict__ vf,
                                              const float* __restrict__ cs, const float* __restrict__ sn,
                                              F16* __restrict__ qg, F16* __restrict__ kg,
                                              F16* __restrict__ vtg, float QS) {
  __shared__ float smem[8256];               // rope: sq[1024]+sk[1024]; vtrans: [64][129]
  const int bid = blockIdx.x;
  const int tid = threadIdx.x;
  if (bid < 8192) {
    float* sq = smem;
    float* sk = smem + 1024;
    const int b = bid >> 11, t = bid & 2047;
    {
      h4v qi = ((const h4v*)(qf + (size_t)bid * 1024))[tid];
      h4v ki = ((const h4v*)(kf + (size_t)bid * 1024))[tid];
#pragma unroll
      for (int j = 0; j < 4; ++j) { sq[tid * 4 + j] = (float)qi[j]; sk[tid * 4 + j] = (float)ki[j]; }
    }
    __syncthreads();
    const int i0 = tid * 4;
    float4 c4 = ((const float4*)(cs + (size_t)t * 1024))[tid];
    float4 s4 = ((const float4*)(sn + (size_t)t * 1024))[tid];
    float cc[4] = {c4.x, c4.y, c4.z, c4.w};
    float ss[4] = {s4.x, s4.y, s4.z, s4.w};
    h4v qv, kv;
#pragma unroll
    for (int j = 0; j < 4; ++j) {
      int i = i0 + j;
      float zq, zk;
      if (i < 512) { zq = sq[i] * cc[j] - sq[2 * i + 1] * ss[j];          // rot[i] = -z[2i+1]
                     zk = sk[i] * cc[j] - sk[2 * i + 1] * ss[j]; }
      else         { zq = sq[i] * cc[j] + sq[2 * (i - 512)] * ss[j];      // rot[512+i'] = z[2i']
                     zk = sk[i] * cc[j] + sk[2 * (i - 512)] * ss[j]; }
      qv[j] = (F16)(zq * QS);
      kv[j] = (F16)zk;
    }
    const int n = i0 >> 7, hh = i0 & 127;
    const size_t o = ((size_t)(b * 8 + n) * 2048 + t) * 128 + hh;
    *(h4v*)(qg + o) = qv;
    *(h4v*)(kg + o) = kv;
  } else {
    const int vb = bid - 8192;               // (b*8+n)*32 + tt
    const int tt = vb & 31, bn = vb >> 5;
    const int b = bn >> 3, n = bn & 7;
    const int t0 = tt * 64;
    float (*s)[129] = (float(*)[129])smem;
#pragma unroll
    for (int r8 = 0; r8 < 4; ++r8) {
      int row = r8 * 16 + (tid >> 4);
      int c8 = tid & 15;
      h8v v = *(const h8v*)(vf + ((size_t)b * 2048 + t0 + row) * 1024 + n * 128 + c8 * 8);
#pragma unroll
      for (int k = 0; k < 8; ++k) s[row][c8 * 8 + k] = (float)v[k];
    }
    __syncthreads();
    const int h = tid >> 1, half = tid & 1;
    const size_t ob = ((size_t)bn * 128 + h) * 2048 + t0 + half * 32;
    h8v o[4];
#pragma unroll
    for (int j = 0; j < 32; ++j) o[j >> 3][j & 7] = (F16)s[half * 32 + j][h];
#pragma unroll
    for (int jj = 0; jj < 4; ++jj) *(h8v*)(vtg + ob + jj * 8) = o[jj];
  }
}

// ---------------- flash attention, fp16, QBLK=128 (8 waves), kv-split LPT ----------------
// 768 jobs (24 ords x 32 bn), 3 blocks/CU, per-CU kv-tile sum == 34.
// seg 0/1 jobs write fp32 partials (O,m,l); seg 2 writes Out directly.
__global__ void __launch_bounds__(512, 6) k_attn(const F16* __restrict__ Q, const F16* __restrict__ K,
                                                 const F16* __restrict__ Vt, float* __restrict__ Out,
                                                 float* __restrict__ Pot, float2* __restrict__ Pml) {
  const int bid = blockIdx.x;
  const int bn = bid & 31;                   // b*8+n
  const int ord = bid >> 5;                  // [0,24)
  const int qt = QT_TAB[ord];
  const int seg = SEG_TAB[ord];
  const int b = bn >> 3, n = bn & 7;
  const int q0 = qt * 128;
  const int kv0 = (seg == 1) ? qt + 1 : 0;
  const int kv1 = (seg == 0) ? qt + 1 : 2 * qt + 2;
  const int tid = threadIdx.x;
  const int lane = tid & 63, w = tid >> 6;   // w in [0,8)
  const int l15 = lane & 15, g = lane >> 4;

  __shared__ F16 sm[24576];                  // 48KB -> 3 blocks/CU
  F16* sK = sm;                              // [64][128] fp16, 16 16B-units/row, unit^=(row&15)
  F16* sV = sm + 8192;                       // [128][64] fp16, 8 units/row, unit^=(row&7)
  F16* sP = sm + 16384 + w * 1024;           // wave-private [16 q][64 kk]

  // Q fragments; q-row = q0 + w*16 + l15
  h8v fq[4];
  {
    const size_t qoff = ((size_t)bn * 2048 + (q0 + w * 16 + l15)) * 128 + g * 8;
#pragma unroll
    for (int hs = 0; hs < 4; ++hs) fq[hs] = *(const h8v*)(Q + qoff + hs * 32);
  }

  // hoisted staging pointers: 2 phases x {K,V}; bump by constant strides per kv-step
  const size_t kbase = (size_t)bn * 2048 * 128;   // same flat base for K ([t][h]) and Vt ([h][t])
  const F16* kS[2]; const F16* vS[2]; F16* kD[2]; F16* vD[2];
#pragma unroll
  for (int p = 0; p < 2; ++p) {
    int u = p * 512 + tid;                   // 1024 16B-units per tile
    { int row = u >> 4, jp = u & 15, j = jp ^ (row & 15);
      kS[p] = K + kbase + (size_t)(kv0 * 64 + row) * 128 + j * 8;
      kD[p] = sK + u * 8; }
    { int row = u >> 3, jp = u & 7, j = jp ^ (row & 7);
      vS[p] = Vt + kbase + (size_t)row * 2048 + kv0 * 64 + j * 8;
      vD[p] = sV + u * 8; }
  }

  f32x4 ot[8] = {};                          // Ot[h=hf*16+g*4+r][q=l15]
  float mrun = -1e30f;
  float lrun = 0.f;

  for (int kv = kv0; kv < kv1; ++kv) {
    const int k0 = kv * 64;
    // ---- stage K and Vt tiles (pre-swizzled source, linear LDS dest)
#pragma unroll
    for (int p = 0; p < 2; ++p) {
      gld16(kS[p], kD[p]);
      gld16(vS[p], vD[p]);
      kS[p] += 8192;                         // 64 rows x 128
      vS[p] += 64;                           // 64 cols
    }
    __syncthreads();

    // ---- QK^T (swapped): St[kk][q]
    f32x4 st[4] = {};
#pragma unroll
    for (int f = 0; f < 4; ++f) {
      const int row = f * 16 + l15;
      const F16* bk = sK + row * 128;
#pragma unroll
      for (int hs = 0; hs < 4; ++hs) {
        const int j = (((hs * 4 + g) ^ (row & 15)) * 8);
        st[f] = mfma16(*(const h8v*)(bk + j), fq[hs], st[f]);
      }
    }

    // ---- mask + online softmax (log2 domain, defer-max) + fp16 P to wave-private LDS
    {
      const int qg = q0 + w * 16 + l15;
      if (k0 + 63 > q0 + w * 16) {
#pragma unroll
        for (int f = 0; f < 4; ++f)
#pragma unroll
          for (int r = 0; r < 4; ++r)
            if (k0 + f * 16 + g * 4 + r > qg) st[f][r] = -1e30f;
      }
      float tm = -1e30f;
#pragma unroll
      for (int f = 0; f < 4; ++f)
#pragma unroll
        for (int r = 0; r < 4; ++r) tm = fmaxf(tm, st[f][r]);
      tm = fmaxf(tm, __shfl_xor(tm, 16));
      tm = fmaxf(tm, __shfl_xor(tm, 32));
      float corr = 1.f;
      const bool resc = !__all(tm <= mrun + 8.0f);   // wave-uniform
      if (resc) {
        const float mn = fmaxf(mrun, tm);
        corr = exp2f(mrun - mn);
        mrun = mn;
      }
      float ps = 0.f;
      const int q = l15;
#pragma unroll
      for (int f = 0; f < 4; ++f) {
        h4v p4;
#pragma unroll
        for (int r = 0; r < 4; ++r) {
          float p = exp2f(st[f][r] - mrun);
          ps += p;
          p4[r] = (F16)p;
        }
        const int off = q * 64 + (((2 * f + (g >> 1)) ^ (q & 7)) * 8) + (g & 1) * 4;
        *(h4v*)(sP + off) = p4;
      }
      ps += __shfl_xor(ps, 16);
      ps += __shfl_xor(ps, 32);
      lrun = lrun * corr + ps;
      if (resc) {
#pragma unroll
        for (int hf = 0; hf < 8; ++hf) {
          ot[hf][0] *= corr; ot[hf][1] *= corr;
          ot[hf][2] *= corr; ot[hf][3] *= corr;
        }
      }
    }
    asm volatile("" ::: "memory");   // keep P ds_writes ordered before PV ds_reads (wave-private, HW in-order)

    // ---- PV: Ot[h][q] += Vt * P (wave-private P, no barrier needed)
    h8v fp[2];
    {
      const int q = l15;
#pragma unroll
      for (int c = 0; c < 2; ++c) {
        const int off = q * 64 + (((4 * c + g) ^ (q & 7)) * 8);
        fp[c] = *(const h8v*)(sP + off);
      }
    }
#pragma unroll
    for (int hf = 0; hf < 8; ++hf) {
      const int row = hf * 16 + l15;
      const int sw = row & 7;
#pragma unroll
      for (int c = 0; c < 2; ++c) {
        const int off = row * 64 + (((4 * c + g) ^ sw) * 8);
        ot[hf] = mfma16(*(const h8v*)(sV + off), fp[c], ot[hf]);
      }
    }
    __syncthreads();   // before next tile's staging overwrites sK/sV
  }

  const int ql = w * 16 + l15;               // local q row [0,128)
  if (seg == 2) {
    // ---- normalize, write out[b, t, n*128+h] as float4
    const float inv = 1.0f / lrun;
    const size_t ob = ((size_t)b * 2048 + q0 + ql) * 1024 + n * 128;
#pragma unroll
    for (int hf = 0; hf < 8; ++hf) {
      float4 o4;
      o4.x = ot[hf][0] * inv; o4.y = ot[hf][1] * inv;
      o4.z = ot[hf][2] * inv; o4.w = ot[hf][3] * inv;
      *(float4*)(Out + ob + hf * 16 + g * 4) = o4;
    }
  } else {
    // ---- write unnormalized partial + (m,l)
    const int pq = bn * 8 + (qt - 8);        // [0,256)
    float* pr = Pot + ((size_t)(pq * 2 + seg) * 128 + ql) * 128;
#pragma unroll
    for (int hf = 0; hf < 8; ++hf) {
      float4 o4;
      o4.x = ot[hf][0]; o4.y = ot[hf][1]; o4.z = ot[hf][2]; o4.w = ot[hf][3];
      *(float4*)(pr + hf * 16 + g * 4) = o4;
    }
    if (g == 0) Pml[(pq * 2 + seg) * 128 + ql] = make_float2(mrun, lrun);
  }
}

// ---------------- merge two kv-half partials -> Out ----------------
__global__ void __launch_bounds__(256) k_merge(const float* __restrict__ Pot,
                                               const float2* __restrict__ Pml,
                                               float* __restrict__ Out) {
  const int pq = blockIdx.x;                 // [0,256): bn*8 + (qt-8)
  const int bn = pq >> 3, qt = (pq & 7) + 8;
  const int b = bn >> 3, n = bn & 7;
  const int t = threadIdx.x;
  const int q = t >> 1, hb = (t & 1) * 64;
  const float2 ml0 = Pml[(pq * 2 + 0) * 128 + q];
  const float2 ml1 = Pml[(pq * 2 + 1) * 128 + q];
  const float M = fmaxf(ml0.x, ml1.x);
  const float s0 = exp2f(ml0.x - M), s1 = exp2f(ml1.x - M);
  const float inv = 1.0f / (ml0.y * s0 + ml1.y * s1);
  const float4* p0 = (const float4*)(Pot + ((size_t)(pq * 2 + 0) * 128 + q) * 128 + hb);
  const float4* p1 = (const float4*)(Pot + ((size_t)(pq * 2 + 1) * 128 + q) * 128 + hb);
  float4* op = (float4*)(Out + ((size_t)b * 2048 + qt * 128 + q) * 1024 + n * 128 + hb);
#pragma unroll
  for (int j = 0; j < 16; ++j) {
    float4 a = p0[j], c = p1[j], o4;
    o4.x = (a.x * s0 + c.x * s1) * inv;
    o4.y = (a.y * s0 + c.y * s1) * inv;
    o4.z = (a.z * s0 + c.z * s1) * inv;
    o4.w = (a.w * s0 + c.w * s1) * inv;
    op[j] = o4;
  }
}

// ---------------- host ----------------
extern "C" void kernel_launch(void* const* d_in, const int* in_sizes, int n_in,
                              void* d_out, int out_size, void* d_ws, size_t ws_size,
                              hipStream_t stream) {
  const float* x  = (const float*)d_in[0];
  const float* wq = (const float*)d_in[1];
  const float* wk = (const float*)d_in[2];
  const float* wv = (const float*)d_in[3];
  const float* cs = (const float*)d_in[4];
  const float* sn = (const float*)d_in[5];
  float* out = (float*)d_out;

  // Workspace (peak 141,033,472 B). qg aliases xh (dead after GEMM); partials at tail.
  F16* xh  = (F16*)d_ws;               // 16,777,216 B
  F16* wh  = xh + 8388608;             //  6,291,456 B (wq,wk,wv contiguous)
  F16* qf  = wh + 3145728;             // 16,777,216 B
  F16* kf  = qf + 8388608;             // 16,777,216 B
  F16* vf  = kf + 8388608;             // 16,777,216 B
  F16* kg  = vf + 8388608;             // 16,777,216 B
  F16* vtg = kg + 8388608;             // 16,777,216 B
  F16* qg  = xh;                       // alias
  float*  pot = (float*)(vtg + 8388608);   // 33,554,432 B (256 pairs x 2 x 128x128 f32)
  float2* pml = (float2*)(pot + 8388608);  //    524,288 B

  if (ws_size < (size_t)141033472) return;  // insufficient scratch -> clean validation failure

  const float QS = 0.08838834764831845f * 1.4426950408889634f;  // 1/sqrt(128) * log2(e)

  k_split_all<<<5632, 256, 0, stream>>>(x, wq, wk, wv, xh, wh);
  k_gemm_qkv<<<1536, 256, 0, stream>>>(xh, wh, qf, kf, vf);
  k_prep<<<9216, 256, 0, stream>>>(qf, kf, vf, cs, sn, qg, kg, vtg, QS);
  k_attn<<<768, 512, 0, stream>>>(qg, kg, vtg, out, pot, pml);
  k_merge<<<256, 256, 0, stream>>>(pot, pml, out);
}